// Round 12
// baseline (273.913 us; speedup 1.0000x reference)
//
#include <hip/hip_runtime.h>
#include <hip/hip_bf16.h>
#include <cmath>

// SparseAttentionBlock: B=2, L=4096, D=512, H=8, dh=64
// Inputs/outputs fp32; internal GEMM pipeline bf16; residual spine fp32.

#define L_SEQ 4096
#define D_MODEL 512
#define N_HEADS 8
#define D_HEAD 64
#define QKV_LD 1536

typedef __attribute__((ext_vector_type(8))) short bf16x8;
typedef __attribute__((ext_vector_type(4))) float f32x4;
typedef __attribute__((ext_vector_type(4))) unsigned u32x4;

__device__ __forceinline__ __hip_bfloat16 f2bf(float v) { return __float2bfloat16(v); }

__device__ __forceinline__ float exp2_raw(float x) {
  float r;
  asm("v_exp_f32 %0, %1" : "=v"(r) : "v"(x));
  return r;  // 2^x, HW transcendental
}

__device__ __forceinline__ void gl_lds16(const __hip_bfloat16* g, __hip_bfloat16* l) {
  __builtin_amdgcn_global_load_lds((__attribute__((address_space(1))) void*)g,
                                   (__attribute__((address_space(3))) void*)l, 16, 0, 0);
}

// ---------------- prep: weight cvt (fp32->bf16) + bias prep + LN1, ONE launch ------------
// blocks [0,3328): cvt/bias (per-thread branch on i);  blocks [3328, 11520): LN1 rows.
__global__ __launch_bounds__(256) void prep_kernel(const float* __restrict__ s0, __hip_bfloat16* __restrict__ d0,
                                                   const float* __restrict__ s1, __hip_bfloat16* __restrict__ d1,
                                                   const float* __restrict__ s2, __hip_bfloat16* __restrict__ d2,
                                                   const float* __restrict__ s3, __hip_bfloat16* __restrict__ d3,
                                                   const float* __restrict__ ts,
                                                   const float* __restrict__ mask,
                                                   const float* __restrict__ decay_rate,
                                                   float* __restrict__ biasH,
                                                   const float* __restrict__ x,
                                                   const float* __restrict__ ln1_g,
                                                   const float* __restrict__ ln1_b,
                                                   __hip_bfloat16* __restrict__ xn) {
  if (blockIdx.x < 3328) {
    const int i = blockIdx.x * 256 + threadIdx.x;
    if (i < 786432) {
      const float* s;
      __hip_bfloat16* d;
      int off;
      if (i < 196608) { s = s0; d = d0; off = i; }
      else if (i < 262144) { s = s1; d = d1; off = i - 196608; }
      else if (i < 524288) { s = s2; d = d2; off = i - 262144; }
      else { s = s3; d = d3; off = i - 524288; }
      const float4 v = ((const float4*)s)[off];
      d[4 * off + 0] = f2bf(v.x);
      d[4 * off + 1] = f2bf(v.y);
      d[4 * off + 2] = f2bf(v.z);
      d[4 * off + 3] = f2bf(v.w);
    } else {
      const int idx = i - 786432;  // 65536 = 2*8*4096
      const int col = idx & 4095;
      const int h = (idx >> 12) & 7;
      const int b = idx >> 15;
      const float LOG2E = 1.4426950408889634f;
      const float dfac = log1pf(expf(decay_rate[h])) * (1.0f / 24.0f) * LOG2E;
      const float m = mask[b * 4096 + col];
      biasH[idx] = dfac * ts[b * 4096 + col] + (m != 0.f ? 0.f : -1e30f);
    }
  } else {
    const int row = blockIdx.x - 3328;
    const int t = threadIdx.x;
    const float* xr = x + (size_t)row * D_MODEL;
    float v0 = xr[t];
    float v1 = xr[t + 256];
    float s = v0 + v1;
    float qq = v0 * v0 + v1 * v1;
    for (int off = 32; off > 0; off >>= 1) {
      s += __shfl_xor(s, off);
      qq += __shfl_xor(qq, off);
    }
    __shared__ float red[8];
    const int wid = t >> 6;
    if ((t & 63) == 0) { red[wid] = s; red[4 + wid] = qq; }
    __syncthreads();
    s = red[0] + red[1] + red[2] + red[3];
    qq = red[4] + red[5] + red[6] + red[7];
    const float mu = s * (1.0f / 512.0f);
    const float var = fmaxf(qq * (1.0f / 512.0f) - mu * mu, 0.0f);
    const float rstd = rsqrtf(var + 1e-5f);
    __hip_bfloat16* orow = xn + (size_t)row * D_MODEL;
    orow[t] = f2bf((v0 - mu) * rstd * ln1_g[t] + ln1_b[t]);
    orow[t + 256] = f2bf((v1 - mu) * rstd * ln1_g[t + 256] + ln1_b[t + 256]);
  }
}

// ---------------- LayerNorm: fp32 in -> bf16 out (ln2) ----------------
__global__ __launch_bounds__(256) void ln_kernel(const float* __restrict__ x,
                                                 const float* __restrict__ g,
                                                 const float* __restrict__ b,
                                                 __hip_bfloat16* __restrict__ out) {
  const int row = blockIdx.x;
  const int t = threadIdx.x;
  const float* xr = x + (size_t)row * D_MODEL;
  float v0 = xr[t];
  float v1 = xr[t + 256];
  float s = v0 + v1;
  float qq = v0 * v0 + v1 * v1;
  for (int off = 32; off > 0; off >>= 1) {
    s += __shfl_xor(s, off);
    qq += __shfl_xor(qq, off);
  }
  __shared__ float red[8];
  const int wid = t >> 6;
  if ((t & 63) == 0) { red[wid] = s; red[4 + wid] = qq; }
  __syncthreads();
  s = red[0] + red[1] + red[2] + red[3];
  qq = red[4] + red[5] + red[6] + red[7];
  const float mu = s * (1.0f / 512.0f);
  const float var = fmaxf(qq * (1.0f / 512.0f) - mu * mu, 0.0f);
  const float rstd = rsqrtf(var + 1e-5f);
  __hip_bfloat16* orow = out + (size_t)row * D_MODEL;
  orow[t] = f2bf((v0 - mu) * rstd * g[t] + b[t]);
  orow[t + 256] = f2bf((v1 - mu) * rstd * g[t + 256] + b[t + 256]);
}

// ---------------- GEMM 128x128: C[M,N] = A[M,K] @ B[N,K]^T, bf16 in, fp32 accum ---------
// SINGLE-barrier 3-buffer K-loop: per iter {barrier; counted vmcnt; ds_reads+MFMA;
// stage(it+2)}. The old trailing barrier is unnecessary: every wave's ds_reads retire
// before its MFMAs issue (compiler lgkm waits), hence before it reaches the next
// barrier; stage(it+2) is pinned after the top barrier by the vmcnt asm "memory"
// clobber, so iter-(it-1) readers of buf[(it+2)%3] (same buffer mod 3) are done.
// 3 buffers give the prefetch ~2 iterations of flight (vs <1 before).
// EPI 0: store bf16   2: silu, store bf16
// EPI 4 (gemm0+vtrans fusion): n0<1024 -> qkv store; n0>=1024 -> V direct to
//   vt[b,h,dh, sigma-permuted L]; sigma: [.][a2][q1][q0][a1][a0]->[.][q1][q0][a2][a1][a0].
template <int EPI>
__global__ __launch_bounds__(256) void gemm_kernel(const __hip_bfloat16* __restrict__ A,
                                                   const __hip_bfloat16* __restrict__ B,
                                                   int M, int N, int K,
                                                   __hip_bfloat16* __restrict__ vtout,
                                                   void* __restrict__ C) {
  __shared__ __align__(16) __hip_bfloat16 As[3][128 * 32];
  __shared__ __align__(16) __hip_bfloat16 Bs[3][128 * 32];
  const int tid = threadIdx.x;
  const int lane = tid & 63, w = tid >> 6;
  const int m0 = blockIdx.y * 128, n0 = blockIdx.x * 128;
  const int wm = (w >> 1) * 64, wn = (w & 1) * 64;
  const int r = lane & 15, q = lane >> 4;

  f32x4 acc[4][4];
  const f32x4 zz = {0.f, 0.f, 0.f, 0.f};
  for (int i = 0; i < 4; i++)
    for (int j = 0; j < 4; j++) acc[i][j] = zz;

  const int c0 = tid, c1 = 256 + tid;
  const int row0 = c0 >> 2, kb0 = (c0 & 3) * 8;
  const int row1 = c1 >> 2, kb1 = (c1 & 3) * 8;

#define GEMM_STAGE(k0, buf)                                                     \
  do {                                                                          \
    gl_lds16(A + (size_t)(m0 + row0) * K + ((k0) + kb0), &As[buf][c0 * 8]);     \
    gl_lds16(B + (size_t)(n0 + row0) * K + ((k0) + kb0), &Bs[buf][c0 * 8]);     \
    gl_lds16(A + (size_t)(m0 + row1) * K + ((k0) + kb1), &As[buf][c1 * 8]);     \
    gl_lds16(B + (size_t)(n0 + row1) * K + ((k0) + kb1), &Bs[buf][c1 * 8]);     \
  } while (0)

  const int niter = K >> 5;
  GEMM_STAGE(0, 0);
  if (niter > 1) GEMM_STAGE(32, 1);
  for (int it = 0; it < niter; it++) {
    const int cur = it % 3;
    __builtin_amdgcn_s_barrier();  // all waves' iter-(it-1) LDS reads retired before here
    if (it + 1 < niter) {
      asm volatile("s_waitcnt vmcnt(4)" ::: "memory");  // stage(it) landed; stage(it+1) flies
    } else {
      asm volatile("s_waitcnt vmcnt(0)" ::: "memory");
    }
    bf16x8 af[4], bfr[4];
    for (int mi = 0; mi < 4; mi++)
      af[mi] = *(const bf16x8*)(&As[cur][(wm + mi * 16 + r) * 32 + q * 8]);
    for (int ni = 0; ni < 4; ni++)
      bfr[ni] = *(const bf16x8*)(&Bs[cur][(wn + ni * 16 + r) * 32 + q * 8]);
    for (int mi = 0; mi < 4; mi++)
      for (int ni = 0; ni < 4; ni++)
        acc[mi][ni] = __builtin_amdgcn_mfma_f32_16x16x32_bf16(af[mi], bfr[ni], acc[mi][ni], 0, 0, 0);
    if (it + 2 < niter) GEMM_STAGE((it + 2) << 5, (it + 2) % 3);
  }
#undef GEMM_STAGE

  for (int mi = 0; mi < 4; mi++)
    for (int ni = 0; ni < 4; ni++)
      for (int j = 0; j < 4; j++) {
        const int gm = m0 + wm + mi * 16 + q * 4 + j;
        const int gn = n0 + wn + ni * 16 + r;
        float v = acc[mi][ni][j];
        const size_t idx = (size_t)gm * N + gn;
        if (EPI == 0) {
          ((__hip_bfloat16*)C)[idx] = f2bf(v);
        } else if (EPI == 2) {
          v = v / (1.0f + expf(-v));
          ((__hip_bfloat16*)C)[idx] = f2bf(v);
        } else {  // EPI == 4
          if (n0 < 1024) {
            ((__hip_bfloat16*)C)[idx] = f2bf(v);
          } else {
            const int bb = gm >> 12, ll = gm & 4095;
            const int hd = gn - 1024;  // h*64 + d
            const int kin = ll & 63;
            const int sl = (kin & 0x23) | ((kin & 0x10) >> 2) | ((kin & 0x0c) << 1);
            vtout[(size_t)(bb * 512 + hd) * 4096 + (ll & ~63) + sl] = f2bf(v);
          }
        }
      }
}

// ---------------- GEMM 64x128 (+residual fp32 epilogue), same single-barrier loop --------
__global__ __launch_bounds__(256) void gemm_res64_kernel(const __hip_bfloat16* __restrict__ A,
                                                         const __hip_bfloat16* __restrict__ B,
                                                         int M, int N, int K,
                                                         const float* __restrict__ aux,
                                                         float* __restrict__ C) {
  __shared__ __align__(16) __hip_bfloat16 As[3][64 * 32];
  __shared__ __align__(16) __hip_bfloat16 Bs[3][128 * 32];
  const int tid = threadIdx.x;
  const int lane = tid & 63, w = tid >> 6;
  const int m0 = blockIdx.y * 64, n0 = blockIdx.x * 128;
  const int wm = (w >> 1) * 32, wn = (w & 1) * 64;
  const int r = lane & 15, q = lane >> 4;

  f32x4 acc[2][4];
  const f32x4 zz = {0.f, 0.f, 0.f, 0.f};
  for (int i = 0; i < 2; i++)
    for (int j = 0; j < 4; j++) acc[i][j] = zz;

  const int rowA = tid >> 2, kbA = (tid & 3) * 8;     // A: 64 rows x 4 chunks = 256
  const int c0 = tid, c1 = 256 + tid;                 // B: 128 rows x 4 chunks = 512
  const int rowB0 = c0 >> 2, kb0 = (c0 & 3) * 8;
  const int rowB1 = c1 >> 2, kb1 = (c1 & 3) * 8;

#define GEMM_STAGE64(k0, buf)                                                    \
  do {                                                                           \
    gl_lds16(A + (size_t)(m0 + rowA) * K + ((k0) + kbA), &As[buf][tid * 8]);     \
    gl_lds16(B + (size_t)(n0 + rowB0) * K + ((k0) + kb0), &Bs[buf][c0 * 8]);     \
    gl_lds16(B + (size_t)(n0 + rowB1) * K + ((k0) + kb1), &Bs[buf][c1 * 8]);     \
  } while (0)

  const int niter = K >> 5;
  GEMM_STAGE64(0, 0);
  if (niter > 1) GEMM_STAGE64(32, 1);
  for (int it = 0; it < niter; it++) {
    const int cur = it % 3;
    __builtin_amdgcn_s_barrier();
    if (it + 1 < niter) {
      asm volatile("s_waitcnt vmcnt(3)" ::: "memory");  // stage(it) landed; stage(it+1) flies
    } else {
      asm volatile("s_waitcnt vmcnt(0)" ::: "memory");
    }
    bf16x8 af[2], bfr[4];
    for (int mi = 0; mi < 2; mi++)
      af[mi] = *(const bf16x8*)(&As[cur][(wm + mi * 16 + r) * 32 + q * 8]);
    for (int ni = 0; ni < 4; ni++)
      bfr[ni] = *(const bf16x8*)(&Bs[cur][(wn + ni * 16 + r) * 32 + q * 8]);
    for (int mi = 0; mi < 2; mi++)
      for (int ni = 0; ni < 4; ni++)
        acc[mi][ni] = __builtin_amdgcn_mfma_f32_16x16x32_bf16(af[mi], bfr[ni], acc[mi][ni], 0, 0, 0);
    if (it + 2 < niter) GEMM_STAGE64((it + 2) << 5, (it + 2) % 3);
  }
#undef GEMM_STAGE64

  for (int mi = 0; mi < 2; mi++)
    for (int ni = 0; ni < 4; ni++)
      for (int j = 0; j < 4; j++) {
        const int gm = m0 + wm + mi * 16 + q * 4 + j;
        const int gn = n0 + wn + ni * 16 + r;
        const size_t idx = (size_t)gm * N + gn;
        C[idx] = acc[mi][ni][j] + aux[idx];
      }
}

// ---------------- Flash attention (R8 config — proven 59 us, unchanged) -----------------
// 512 blocks x 8 waves, 2 blocks/CU = 16 waves/CU (4/SIMD). Waves 0-3 = group A (q-tile
// pr), waves 4-7 = group B (q-tile 63-pr); shared staging stream of ntB 128-key tiles.
__device__ __forceinline__ void stage_kv128(int w, int lane, int key0,
                                            const __hip_bfloat16* __restrict__ Kg,
                                            const __hip_bfloat16* __restrict__ Vg,
                                            __hip_bfloat16* Ks, __hip_bfloat16* Vs) {
  const int krow_in = lane >> 3;
  const int kcs = (lane & 7) ^ krow_in;
  const int vrow_in = lane >> 4;
  const int vch = lane & 15;
#pragma unroll
  for (int ii = 0; ii < 2; ii++) {
    const int i = w * 2 + ii;
    const int krow = i * 8 + krow_in;  // 0..127
    gl_lds16(Kg + (size_t)(key0 + krow) * QKV_LD + kcs * 8, Ks + i * 512 + lane * 8);
    const int vrow = i * 4 + vrow_in;  // 0..63
    const int vcs = vch ^ (vrow & 7);
    gl_lds16(Vg + (size_t)vrow * L_SEQ + key0 + vcs * 8, Vs + i * 512 + lane * 8);
  }
}

// Swapped QK^T over 128 keys: lane (r,q) holds S[key=16hc+4q+j][query=r], hc 0..7.
// Fixed-reference log2-domain softmax (normalizer cancels; bias bounded +42).
// P lane-local -> PV A-fragments via sigma-permuted V. Rowsum via ones-MFMA.
template <bool CAUSAL>
__device__ __forceinline__ void attn_tile128(int key0, int lw0, int r, int q,
                                             const __hip_bfloat16* Ks,
                                             const __hip_bfloat16* Vs,
                                             const float* biasLds,
                                             float scale2,
                                             const bf16x8& qf0, const bf16x8& qf1,
                                             const bf16x8& onesf,
                                             f32x4* o, f32x4& ls) {
  const int r7 = r & 7;
  const f32x4 zz = {0.f, 0.f, 0.f, 0.f};
  f32x4 bias4[8];
#pragma unroll
  for (int hc = 0; hc < 8; hc++)
    bias4[hc] = *(const f32x4*)(biasLds + key0 + hc * 16 + q * 4);
  f32x4 s[8];
  __builtin_amdgcn_s_setprio(1);
#pragma unroll
  for (int hc = 0; hc < 8; hc++) {
    const __hip_bfloat16* kr = Ks + (hc * 16 + r) * 64;
    bf16x8 k0 = *(const bf16x8*)(kr + ((q ^ r7) * 8));
    bf16x8 k1 = *(const bf16x8*)(kr + (((q + 4) ^ r7) * 8));
    f32x4 a = zz;
    a = __builtin_amdgcn_mfma_f32_16x16x32_bf16(k0, qf0, a, 0, 0, 0);
    a = __builtin_amdgcn_mfma_f32_16x16x32_bf16(k1, qf1, a, 0, 0, 0);
    s[hc] = a;
  }
  __builtin_amdgcn_s_setprio(0);
  float p[8][4];
#pragma unroll
  for (int hc = 0; hc < 8; hc++)
#pragma unroll
    for (int j = 0; j < 4; j++) {
      float pv = exp2_raw(fmaf(s[hc][j], scale2, bias4[hc][j]));
      if (CAUSAL) pv = (key0 + hc * 16 + q * 4 + j <= lw0 + r) ? pv : 0.f;
      p[hc][j] = pv;
    }
  bf16x8 pa[4];
#pragma unroll
  for (int kc = 0; kc < 4; kc++) {
    u32x4 pw;
    unsigned w0, w1, w2, w3;
    asm("v_cvt_pk_bf16_f32 %0, %1, %2" : "=v"(w0) : "v"(p[2 * kc][0]), "v"(p[2 * kc][1]));
    asm("v_cvt_pk_bf16_f32 %0, %1, %2" : "=v"(w1) : "v"(p[2 * kc][2]), "v"(p[2 * kc][3]));
    asm("v_cvt_pk_bf16_f32 %0, %1, %2" : "=v"(w2) : "v"(p[2 * kc + 1][0]), "v"(p[2 * kc + 1][1]));
    asm("v_cvt_pk_bf16_f32 %0, %1, %2" : "=v"(w3) : "v"(p[2 * kc + 1][2]), "v"(p[2 * kc + 1][3]));
    pw[0] = w0; pw[1] = w1; pw[2] = w2; pw[3] = w3;
    pa[kc] = *(bf16x8*)&pw;
  }
  __builtin_amdgcn_s_setprio(1);
#pragma unroll
  for (int kc = 0; kc < 4; kc++) {
#pragma unroll
    for (int c = 0; c < 4; c++) {
      const __hip_bfloat16* vr = Vs + (c * 16 + r) * 128 + (((kc * 4 + q) ^ r7) * 8);
      bf16x8 vf = *(const bf16x8*)vr;
      o[c] = __builtin_amdgcn_mfma_f32_16x16x32_bf16(pa[kc], vf, o[c], 0, 0, 0);
    }
    ls = __builtin_amdgcn_mfma_f32_16x16x32_bf16(pa[kc], onesf, ls, 0, 0, 0);
  }
  __builtin_amdgcn_s_setprio(0);
}

__global__ __launch_bounds__(512, 4) void attn_kernel(const __hip_bfloat16* __restrict__ qkv,
                                                      const __hip_bfloat16* __restrict__ vt,
                                                      const float* __restrict__ biasH,
                                                      __hip_bfloat16* __restrict__ out) {
  const int blk = blockIdx.x;
  const int bh = blk & 15;
  const int pr = blk >> 4;  // 0..31
  const int b = bh >> 3, h = bh & 7;
  const int tid = threadIdx.x, lane = tid & 63, w = tid >> 6;  // w 0..7
  const int grp = w >> 2, wg = w & 3;
  const int qi = grp ? (63 - pr) : pr;
  const int l0 = qi * 64;
  const int lw0 = l0 + wg * 16;
  const int r = lane & 15, q = lane >> 4;

  __shared__ __align__(16) __hip_bfloat16 Ksm[2][128 * 64];
  __shared__ __align__(16) __hip_bfloat16 Vsm[2][64 * 128];
  __shared__ __align__(16) float biasLds[4096];

  const float LOG2E = 1.4426950408889634f;
  const float scale2 = 0.125f * LOG2E;

  const __hip_bfloat16* Kg = qkv + (size_t)b * L_SEQ * QKV_LD + 512 + h * 64;
  const __hip_bfloat16* Vg = vt + (size_t)bh * 64 * L_SEQ;
  const float* biasHp = biasH + (size_t)bh * L_SEQ;

  stage_kv128(w, lane, 0, Kg, Vg, Ksm[0], Vsm[0]);
#pragma unroll
  for (int ii = 0; ii < 2; ii++) {
    const int fo = (w * 2 + ii) * 256;
    gl_lds16((const __hip_bfloat16*)(biasHp + fo + lane * 4),
             (__hip_bfloat16*)(biasLds + fo + lane * 4));
  }

  bf16x8 qf0, qf1;
  {
    const __hip_bfloat16* qrow = qkv + (size_t)(b * L_SEQ + lw0 + r) * QKV_LD + h * 64 + q * 8;
    qf0 = *(const bf16x8*)qrow;
    qf1 = *(const bf16x8*)(qrow + 32);
  }

  const f32x4 zz = {0.f, 0.f, 0.f, 0.f};
  f32x4 o[4];
  for (int c = 0; c < 4; c++) o[c] = zz;
  f32x4 ls = zz;

  bf16x8 onesf;
  for (int i = 0; i < 8; i++) ((short*)&onesf)[i] = (short)0x3F80;  // bf16 1.0

  const int ntA = (pr >> 1) + 1;
  const int ntB = ((63 - pr) >> 1) + 1;
  const int nt = grp ? ntB : ntA;

  for (int t = 0; t < ntB; t++) {
    const int cur = t & 1;
    if (t + 1 < ntB) {
      stage_kv128(w, lane, (t + 1) << 7, Kg, Vg, Ksm[cur ^ 1], Vsm[cur ^ 1]);
      asm volatile("s_waitcnt vmcnt(4)" ::: "memory");
    } else {
      asm volatile("s_waitcnt vmcnt(0)" ::: "memory");
    }
    __builtin_amdgcn_s_barrier();
    if (t < nt) {
      if (t == nt - 1)
        attn_tile128<true>(t << 7, lw0, r, q, Ksm[cur], Vsm[cur], biasLds, scale2, qf0, qf1,
                           onesf, o, ls);
      else
        attn_tile128<false>(t << 7, lw0, r, q, Ksm[cur], Vsm[cur], biasLds, scale2, qf0, qf1,
                            onesf, o, ls);
    }
    __builtin_amdgcn_s_barrier();
  }

  float invj[4];
  for (int j = 0; j < 4; j++) invj[j] = 1.0f / ls[j];
  for (int c = 0; c < 4; c++)
    for (int j = 0; j < 4; j++) {
      const int rowg = lw0 + q * 4 + j;
      out[(size_t)(b * L_SEQ + rowg) * D_MODEL + h * 64 + c * 16 + r] = f2bf(o[c][j] * invj[j]);
    }
}

// ---------------- Launch ----------------
extern "C" void kernel_launch(void* const* d_in, const int* in_sizes, int n_in,
                              void* d_out, int out_size, void* d_ws, size_t ws_size,
                              hipStream_t stream) {
  const float* x = (const float*)d_in[0];
  const float* ts = (const float*)d_in[1];
  const float* mask = (const float*)d_in[2];
  const float* ln1_g = (const float*)d_in[3];
  const float* ln1_b = (const float*)d_in[4];
  const float* w_qkv = (const float*)d_in[5];
  const float* w_out = (const float*)d_in[6];
  const float* decay = (const float*)d_in[7];
  const float* ln2_g = (const float*)d_in[8];
  const float* ln2_b = (const float*)d_in[9];
  const float* w_ff1 = (const float*)d_in[10];
  const float* w_ff2 = (const float*)d_in[11];

  char* ws = (char*)d_ws;
  // layout (bytes) — total footprint 65,011,712:
  //   [0, 6M)    weights bf16
  //   [6M, 14M)  xn (dead after gemm0)
  //   [14M, 38M) qkv Q/K regions (dead after attn); V region never written (fused to vt)
  //   [38M, 46M) attnout -> h
  //   [46M, 62M) x2 (fp32). Overlaid at its head (disjoint lifetimes, all dead before
  //              gemm<1> writes x2): biasH (256KB) then vt (8MB).
  //   ff1out overlays [6M, 38M)
  __hip_bfloat16* wqkv_b = (__hip_bfloat16*)(ws + 0);
  __hip_bfloat16* wout_b = (__hip_bfloat16*)(ws + 1572864);
  __hip_bfloat16* wff1_b = (__hip_bfloat16*)(ws + 2097152);
  __hip_bfloat16* wff2_b = (__hip_bfloat16*)(ws + 4194304);
  __hip_bfloat16* xn = (__hip_bfloat16*)(ws + 6291456);
  __hip_bfloat16* qkv = (__hip_bfloat16*)(ws + 14680064);
  __hip_bfloat16* attnout = (__hip_bfloat16*)(ws + 39845888);
  __hip_bfloat16* h = attnout;
  __hip_bfloat16* ff1out = (__hip_bfloat16*)(ws + 6291456);
  float* x2 = (float*)(ws + 48234496);
  float* biasH = (float*)(ws + 48234496);                  // [46M, +256KB)
  __hip_bfloat16* vt = (__hip_bfloat16*)(ws + 48496640);   // [46M+256KB, +8MB)
  float* out = (float*)d_out;

  const int M = 2 * L_SEQ;  // 8192

  prep_kernel<<<dim3(11520), dim3(256), 0, stream>>>(w_qkv, wqkv_b, w_out, wout_b,
                                                     w_ff1, wff1_b, w_ff2, wff2_b,
                                                     ts, mask, decay, biasH,
                                                     x, ln1_g, ln1_b, xn);

  gemm_kernel<4><<<dim3(12, 64), dim3(256), 0, stream>>>(xn, wqkv_b, M, 1536, 512, vt, qkv);
  attn_kernel<<<dim3(512), dim3(512), 0, stream>>>(qkv, vt, biasH, attnout);
  gemm_res64_kernel<<<dim3(4, 128), dim3(256), 0, stream>>>(attnout, wout_b, M, 512, 512, x, x2);
  ln_kernel<<<dim3(M), dim3(256), 0, stream>>>(x2, ln2_g, ln2_b, h);
  gemm_kernel<2><<<dim3(16, 64), dim3(256), 0, stream>>>(h, wff1_b, M, 2048, 512, nullptr, ff1out);
  gemm_res64_kernel<<<dim3(4, 128), dim3(256), 0, stream>>>(ff1out, wff2_b, M, 512, 2048, x2, out);
}

// Round 13
// 260.274 us; speedup vs baseline: 1.0524x; 1.0524x over previous
//
#include <hip/hip_runtime.h>
#include <hip/hip_bf16.h>
#include <cmath>

// SparseAttentionBlock: B=2, L=4096, D=512, H=8, dh=64
// Inputs/outputs fp32; internal GEMM pipeline bf16; residual spine fp32.

#define L_SEQ 4096
#define D_MODEL 512
#define N_HEADS 8
#define D_HEAD 64
#define QKV_LD 1536

typedef __attribute__((ext_vector_type(8))) short bf16x8;
typedef __attribute__((ext_vector_type(4))) float f32x4;
typedef __attribute__((ext_vector_type(4))) unsigned u32x4;

__device__ __forceinline__ __hip_bfloat16 f2bf(float v) { return __float2bfloat16(v); }

__device__ __forceinline__ float exp2_raw(float x) {
  float r;
  asm("v_exp_f32 %0, %1" : "=v"(r) : "v"(x));
  return r;  // 2^x, HW transcendental
}

__device__ __forceinline__ void gl_lds16(const __hip_bfloat16* g, __hip_bfloat16* l) {
  __builtin_amdgcn_global_load_lds((__attribute__((address_space(1))) void*)g,
                                   (__attribute__((address_space(3))) void*)l, 16, 0, 0);
}

// ---------------- prep: weight cvt (fp32->bf16) + bias prep + LN1, ONE launch ------------
__global__ __launch_bounds__(256) void prep_kernel(const float* __restrict__ s0, __hip_bfloat16* __restrict__ d0,
                                                   const float* __restrict__ s1, __hip_bfloat16* __restrict__ d1,
                                                   const float* __restrict__ s2, __hip_bfloat16* __restrict__ d2,
                                                   const float* __restrict__ s3, __hip_bfloat16* __restrict__ d3,
                                                   const float* __restrict__ ts,
                                                   const float* __restrict__ mask,
                                                   const float* __restrict__ decay_rate,
                                                   float* __restrict__ biasH,
                                                   const float* __restrict__ x,
                                                   const float* __restrict__ ln1_g,
                                                   const float* __restrict__ ln1_b,
                                                   __hip_bfloat16* __restrict__ xn) {
  if (blockIdx.x < 3328) {
    const int i = blockIdx.x * 256 + threadIdx.x;
    if (i < 786432) {
      const float* s;
      __hip_bfloat16* d;
      int off;
      if (i < 196608) { s = s0; d = d0; off = i; }
      else if (i < 262144) { s = s1; d = d1; off = i - 196608; }
      else if (i < 524288) { s = s2; d = d2; off = i - 262144; }
      else { s = s3; d = d3; off = i - 524288; }
      const float4 v = ((const float4*)s)[off];
      d[4 * off + 0] = f2bf(v.x);
      d[4 * off + 1] = f2bf(v.y);
      d[4 * off + 2] = f2bf(v.z);
      d[4 * off + 3] = f2bf(v.w);
    } else {
      const int idx = i - 786432;  // 65536 = 2*8*4096
      const int col = idx & 4095;
      const int h = (idx >> 12) & 7;
      const int b = idx >> 15;
      const float LOG2E = 1.4426950408889634f;
      const float dfac = log1pf(expf(decay_rate[h])) * (1.0f / 24.0f) * LOG2E;
      const float m = mask[b * 4096 + col];
      biasH[idx] = dfac * ts[b * 4096 + col] + (m != 0.f ? 0.f : -1e30f);
    }
  } else {
    const int row = blockIdx.x - 3328;
    const int t = threadIdx.x;
    const float* xr = x + (size_t)row * D_MODEL;
    float v0 = xr[t];
    float v1 = xr[t + 256];
    float s = v0 + v1;
    float qq = v0 * v0 + v1 * v1;
    for (int off = 32; off > 0; off >>= 1) {
      s += __shfl_xor(s, off);
      qq += __shfl_xor(qq, off);
    }
    __shared__ float red[8];
    const int wid = t >> 6;
    if ((t & 63) == 0) { red[wid] = s; red[4 + wid] = qq; }
    __syncthreads();
    s = red[0] + red[1] + red[2] + red[3];
    qq = red[4] + red[5] + red[6] + red[7];
    const float mu = s * (1.0f / 512.0f);
    const float var = fmaxf(qq * (1.0f / 512.0f) - mu * mu, 0.0f);
    const float rstd = rsqrtf(var + 1e-5f);
    __hip_bfloat16* orow = xn + (size_t)row * D_MODEL;
    orow[t] = f2bf((v0 - mu) * rstd * ln1_g[t] + ln1_b[t]);
    orow[t + 256] = f2bf((v1 - mu) * rstd * ln1_g[t + 256] + ln1_b[t + 256]);
  }
}

// ---------------- LayerNorm: fp32 in -> bf16 out (ln2) ----------------
__global__ __launch_bounds__(256) void ln_kernel(const float* __restrict__ x,
                                                 const float* __restrict__ g,
                                                 const float* __restrict__ b,
                                                 __hip_bfloat16* __restrict__ out) {
  const int row = blockIdx.x;
  const int t = threadIdx.x;
  const float* xr = x + (size_t)row * D_MODEL;
  float v0 = xr[t];
  float v1 = xr[t + 256];
  float s = v0 + v1;
  float qq = v0 * v0 + v1 * v1;
  for (int off = 32; off > 0; off >>= 1) {
    s += __shfl_xor(s, off);
    qq += __shfl_xor(qq, off);
  }
  __shared__ float red[8];
  const int wid = t >> 6;
  if ((t & 63) == 0) { red[wid] = s; red[4 + wid] = qq; }
  __syncthreads();
  s = red[0] + red[1] + red[2] + red[3];
  qq = red[4] + red[5] + red[6] + red[7];
  const float mu = s * (1.0f / 512.0f);
  const float var = fmaxf(qq * (1.0f / 512.0f) - mu * mu, 0.0f);
  const float rstd = rsqrtf(var + 1e-5f);
  __hip_bfloat16* orow = out + (size_t)row * D_MODEL;
  orow[t] = f2bf((v0 - mu) * rstd * g[t] + b[t]);
  orow[t + 256] = f2bf((v1 - mu) * rstd * g[t + 256] + b[t + 256]);
}

// ---------------- GEMM 128x128 (2-barrier double-buffer — proven optimum) ---------------
// EPI 0: store bf16
// EPI 4 (gemm0+vtrans fusion): n0<1024 -> qkv store; n0>=1024 -> V direct to
//   vt[b,h,dh, sigma-permuted L]; sigma: [.][a2][q1][q0][a1][a0]->[.][q1][q0][a2][a1][a0].
template <int EPI>
__global__ __launch_bounds__(256) void gemm_kernel(const __hip_bfloat16* __restrict__ A,
                                                   const __hip_bfloat16* __restrict__ B,
                                                   int M, int N, int K,
                                                   __hip_bfloat16* __restrict__ vtout,
                                                   void* __restrict__ C) {
  __shared__ __align__(16) __hip_bfloat16 As[2][128 * 32];
  __shared__ __align__(16) __hip_bfloat16 Bs[2][128 * 32];
  const int tid = threadIdx.x;
  const int lane = tid & 63, w = tid >> 6;
  const int m0 = blockIdx.y * 128, n0 = blockIdx.x * 128;
  const int wm = (w >> 1) * 64, wn = (w & 1) * 64;
  const int r = lane & 15, q = lane >> 4;

  f32x4 acc[4][4];
  const f32x4 zz = {0.f, 0.f, 0.f, 0.f};
  for (int i = 0; i < 4; i++)
    for (int j = 0; j < 4; j++) acc[i][j] = zz;

  const int c0 = tid, c1 = 256 + tid;
  const int row0 = c0 >> 2, kb0 = (c0 & 3) * 8;
  const int row1 = c1 >> 2, kb1 = (c1 & 3) * 8;

#define GEMM_STAGE(k0, buf)                                                     \
  do {                                                                          \
    gl_lds16(A + (size_t)(m0 + row0) * K + ((k0) + kb0), &As[buf][c0 * 8]);     \
    gl_lds16(B + (size_t)(n0 + row0) * K + ((k0) + kb0), &Bs[buf][c0 * 8]);     \
    gl_lds16(A + (size_t)(m0 + row1) * K + ((k0) + kb1), &As[buf][c1 * 8]);     \
    gl_lds16(B + (size_t)(n0 + row1) * K + ((k0) + kb1), &Bs[buf][c1 * 8]);     \
  } while (0)

  GEMM_STAGE(0, 0);
  const int niter = K >> 5;
  for (int it = 0; it < niter; it++) {
    const int cur = it & 1;
    if (it + 1 < niter) {
      GEMM_STAGE((it + 1) << 5, cur ^ 1);
      asm volatile("s_waitcnt vmcnt(4)" ::: "memory");  // own iter-it loads retired
    } else {
      asm volatile("s_waitcnt vmcnt(0)" ::: "memory");
    }
    __builtin_amdgcn_s_barrier();  // all waves' iter-it stage complete
    bf16x8 af[4], bfr[4];
    for (int mi = 0; mi < 4; mi++)
      af[mi] = *(const bf16x8*)(&As[cur][(wm + mi * 16 + r) * 32 + q * 8]);
    for (int ni = 0; ni < 4; ni++)
      bfr[ni] = *(const bf16x8*)(&Bs[cur][(wn + ni * 16 + r) * 32 + q * 8]);
    for (int mi = 0; mi < 4; mi++)
      for (int ni = 0; ni < 4; ni++)
        acc[mi][ni] = __builtin_amdgcn_mfma_f32_16x16x32_bf16(af[mi], bfr[ni], acc[mi][ni], 0, 0, 0);
    __builtin_amdgcn_s_barrier();  // reads of buf[cur] done before it+1 overwrites it
  }
#undef GEMM_STAGE

  for (int mi = 0; mi < 4; mi++)
    for (int ni = 0; ni < 4; ni++)
      for (int j = 0; j < 4; j++) {
        const int gm = m0 + wm + mi * 16 + q * 4 + j;
        const int gn = n0 + wn + ni * 16 + r;
        float v = acc[mi][ni][j];
        const size_t idx = (size_t)gm * N + gn;
        if (EPI == 0) {
          ((__hip_bfloat16*)C)[idx] = f2bf(v);
        } else {  // EPI == 4
          if (n0 < 1024) {
            ((__hip_bfloat16*)C)[idx] = f2bf(v);
          } else {
            const int bb = gm >> 12, ll = gm & 4095;
            const int hd = gn - 1024;  // h*64 + d
            const int kin = ll & 63;
            const int sl = (kin & 0x23) | ((kin & 0x10) >> 2) | ((kin & 0x0c) << 1);
            vtout[(size_t)(bb * 512 + hd) * 4096 + (ll & ~63) + sl] = f2bf(v);
          }
        }
      }
}

// ---------------- GEMM 256x128 + silu (gemm2): 2x arithmetic intensity per staged byte --
// 512 threads (8 waves: 4m x 2n), wave owns 64x64. BK=32, double-buffered (48KB LDS),
// 2 blocks/CU = 16 waves/CU. Per iter: 24KB staged for the same 16 MFMA/wave as the
// 128^2 kernel's 32KB (A-panel reuse doubles). 3 gl_lds/thread -> vmcnt(3).
__global__ __launch_bounds__(512, 4) void gemm256_silu_kernel(const __hip_bfloat16* __restrict__ A,
                                                              const __hip_bfloat16* __restrict__ B,
                                                              int M, int N, int K,
                                                              __hip_bfloat16* __restrict__ C) {
  __shared__ __align__(16) __hip_bfloat16 As[2][256 * 32];
  __shared__ __align__(16) __hip_bfloat16 Bs[2][128 * 32];
  const int tid = threadIdx.x;
  const int lane = tid & 63, w = tid >> 6;
  const int m0 = blockIdx.y * 256, n0 = blockIdx.x * 128;
  const int wm = (w >> 1) * 64, wn = (w & 1) * 64;
  const int r = lane & 15, q = lane >> 4;

  f32x4 acc[4][4];
  const f32x4 zz = {0.f, 0.f, 0.f, 0.f};
  for (int i = 0; i < 4; i++)
    for (int j = 0; j < 4; j++) acc[i][j] = zz;

  // 1536 16B-chunks per stage (A: 1024 = 256 rows x 4, B: 512 = 128 rows x 4), 3/thread
#define GEMM_STAGE256(k0, buf)                                                        \
  do {                                                                                \
    _Pragma("unroll")                                                                 \
    for (int i = 0; i < 3; i++) {                                                     \
      const int l = i * 512 + tid;                                                    \
      if (l < 1024) {                                                                 \
        gl_lds16(A + (size_t)(m0 + (l >> 2)) * K + ((k0) + (l & 3) * 8),              \
                 &As[buf][l * 8]);                                                    \
      } else {                                                                        \
        const int lb = l - 1024;                                                      \
        gl_lds16(B + (size_t)(n0 + (lb >> 2)) * K + ((k0) + (lb & 3) * 8),            \
                 &Bs[buf][lb * 8]);                                                   \
      }                                                                               \
    }                                                                                 \
  } while (0)

  GEMM_STAGE256(0, 0);
  const int niter = K >> 5;
  for (int it = 0; it < niter; it++) {
    const int cur = it & 1;
    if (it + 1 < niter) {
      GEMM_STAGE256((it + 1) << 5, cur ^ 1);
      asm volatile("s_waitcnt vmcnt(3)" ::: "memory");  // own iter-it loads retired
    } else {
      asm volatile("s_waitcnt vmcnt(0)" ::: "memory");
    }
    __builtin_amdgcn_s_barrier();
    bf16x8 af[4], bfr[4];
    for (int mi = 0; mi < 4; mi++)
      af[mi] = *(const bf16x8*)(&As[cur][(wm + mi * 16 + r) * 32 + q * 8]);
    for (int ni = 0; ni < 4; ni++)
      bfr[ni] = *(const bf16x8*)(&Bs[cur][(wn + ni * 16 + r) * 32 + q * 8]);
    for (int mi = 0; mi < 4; mi++)
      for (int ni = 0; ni < 4; ni++)
        acc[mi][ni] = __builtin_amdgcn_mfma_f32_16x16x32_bf16(af[mi], bfr[ni], acc[mi][ni], 0, 0, 0);
    __builtin_amdgcn_s_barrier();
  }
#undef GEMM_STAGE256

  for (int mi = 0; mi < 4; mi++)
    for (int ni = 0; ni < 4; ni++)
      for (int j = 0; j < 4; j++) {
        const int gm = m0 + wm + mi * 16 + q * 4 + j;
        const int gn = n0 + wn + ni * 16 + r;
        float v = acc[mi][ni][j];
        v = v / (1.0f + expf(-v));
        C[(size_t)gm * N + gn] = f2bf(v);
      }
}

// ---------------- GEMM 64x128 (+residual fp32 epilogue), 2-barrier double-buffer --------
__global__ __launch_bounds__(256) void gemm_res64_kernel(const __hip_bfloat16* __restrict__ A,
                                                         const __hip_bfloat16* __restrict__ B,
                                                         int M, int N, int K,
                                                         const float* __restrict__ aux,
                                                         float* __restrict__ C) {
  __shared__ __align__(16) __hip_bfloat16 As[2][64 * 32];
  __shared__ __align__(16) __hip_bfloat16 Bs[2][128 * 32];
  const int tid = threadIdx.x;
  const int lane = tid & 63, w = tid >> 6;
  const int m0 = blockIdx.y * 64, n0 = blockIdx.x * 128;
  const int wm = (w >> 1) * 32, wn = (w & 1) * 64;
  const int r = lane & 15, q = lane >> 4;

  f32x4 acc[2][4];
  const f32x4 zz = {0.f, 0.f, 0.f, 0.f};
  for (int i = 0; i < 2; i++)
    for (int j = 0; j < 4; j++) acc[i][j] = zz;

  const int rowA = tid >> 2, kbA = (tid & 3) * 8;     // A: 64 rows x 4 chunks = 256
  const int c0 = tid, c1 = 256 + tid;                 // B: 128 rows x 4 chunks = 512
  const int rowB0 = c0 >> 2, kb0 = (c0 & 3) * 8;
  const int rowB1 = c1 >> 2, kb1 = (c1 & 3) * 8;

#define GEMM_STAGE64(k0, buf)                                                    \
  do {                                                                           \
    gl_lds16(A + (size_t)(m0 + rowA) * K + ((k0) + kbA), &As[buf][tid * 8]);     \
    gl_lds16(B + (size_t)(n0 + rowB0) * K + ((k0) + kb0), &Bs[buf][c0 * 8]);     \
    gl_lds16(B + (size_t)(n0 + rowB1) * K + ((k0) + kb1), &Bs[buf][c1 * 8]);     \
  } while (0)

  GEMM_STAGE64(0, 0);
  const int niter = K >> 5;
  for (int it = 0; it < niter; it++) {
    const int cur = it & 1;
    if (it + 1 < niter) {
      GEMM_STAGE64((it + 1) << 5, cur ^ 1);
      asm volatile("s_waitcnt vmcnt(3)" ::: "memory");  // own iter-it loads retired
    } else {
      asm volatile("s_waitcnt vmcnt(0)" ::: "memory");
    }
    __builtin_amdgcn_s_barrier();
    bf16x8 af[2], bfr[4];
    for (int mi = 0; mi < 2; mi++)
      af[mi] = *(const bf16x8*)(&As[cur][(wm + mi * 16 + r) * 32 + q * 8]);
    for (int ni = 0; ni < 4; ni++)
      bfr[ni] = *(const bf16x8*)(&Bs[cur][(wn + ni * 16 + r) * 32 + q * 8]);
    for (int mi = 0; mi < 2; mi++)
      for (int ni = 0; ni < 4; ni++)
        acc[mi][ni] = __builtin_amdgcn_mfma_f32_16x16x32_bf16(af[mi], bfr[ni], acc[mi][ni], 0, 0, 0);
    __builtin_amdgcn_s_barrier();
  }
#undef GEMM_STAGE64

  for (int mi = 0; mi < 2; mi++)
    for (int ni = 0; ni < 4; ni++)
      for (int j = 0; j < 4; j++) {
        const int gm = m0 + wm + mi * 16 + q * 4 + j;
        const int gn = n0 + wn + ni * 16 + r;
        const size_t idx = (size_t)gm * N + gn;
        C[idx] = acc[mi][ni][j] + aux[idx];
      }
}

// ---------------- Flash attention (R8 config — proven ~58 us, unchanged) ----------------
__device__ __forceinline__ void stage_kv128(int w, int lane, int key0,
                                            const __hip_bfloat16* __restrict__ Kg,
                                            const __hip_bfloat16* __restrict__ Vg,
                                            __hip_bfloat16* Ks, __hip_bfloat16* Vs) {
  const int krow_in = lane >> 3;
  const int kcs = (lane & 7) ^ krow_in;
  const int vrow_in = lane >> 4;
  const int vch = lane & 15;
#pragma unroll
  for (int ii = 0; ii < 2; ii++) {
    const int i = w * 2 + ii;
    const int krow = i * 8 + krow_in;  // 0..127
    gl_lds16(Kg + (size_t)(key0 + krow) * QKV_LD + kcs * 8, Ks + i * 512 + lane * 8);
    const int vrow = i * 4 + vrow_in;  // 0..63
    const int vcs = vch ^ (vrow & 7);
    gl_lds16(Vg + (size_t)vrow * L_SEQ + key0 + vcs * 8, Vs + i * 512 + lane * 8);
  }
}

template <bool CAUSAL>
__device__ __forceinline__ void attn_tile128(int key0, int lw0, int r, int q,
                                             const __hip_bfloat16* Ks,
                                             const __hip_bfloat16* Vs,
                                             const float* biasLds,
                                             float scale2,
                                             const bf16x8& qf0, const bf16x8& qf1,
                                             const bf16x8& onesf,
                                             f32x4* o, f32x4& ls) {
  const int r7 = r & 7;
  const f32x4 zz = {0.f, 0.f, 0.f, 0.f};
  f32x4 bias4[8];
#pragma unroll
  for (int hc = 0; hc < 8; hc++)
    bias4[hc] = *(const f32x4*)(biasLds + key0 + hc * 16 + q * 4);
  f32x4 s[8];
  __builtin_amdgcn_s_setprio(1);
#pragma unroll
  for (int hc = 0; hc < 8; hc++) {
    const __hip_bfloat16* kr = Ks + (hc * 16 + r) * 64;
    bf16x8 k0 = *(const bf16x8*)(kr + ((q ^ r7) * 8));
    bf16x8 k1 = *(const bf16x8*)(kr + (((q + 4) ^ r7) * 8));
    f32x4 a = zz;
    a = __builtin_amdgcn_mfma_f32_16x16x32_bf16(k0, qf0, a, 0, 0, 0);
    a = __builtin_amdgcn_mfma_f32_16x16x32_bf16(k1, qf1, a, 0, 0, 0);
    s[hc] = a;
  }
  __builtin_amdgcn_s_setprio(0);
  float p[8][4];
#pragma unroll
  for (int hc = 0; hc < 8; hc++)
#pragma unroll
    for (int j = 0; j < 4; j++) {
      float pv = exp2_raw(fmaf(s[hc][j], scale2, bias4[hc][j]));
      if (CAUSAL) pv = (key0 + hc * 16 + q * 4 + j <= lw0 + r) ? pv : 0.f;
      p[hc][j] = pv;
    }
  bf16x8 pa[4];
#pragma unroll
  for (int kc = 0; kc < 4; kc++) {
    u32x4 pw;
    unsigned w0, w1, w2, w3;
    asm("v_cvt_pk_bf16_f32 %0, %1, %2" : "=v"(w0) : "v"(p[2 * kc][0]), "v"(p[2 * kc][1]));
    asm("v_cvt_pk_bf16_f32 %0, %1, %2" : "=v"(w1) : "v"(p[2 * kc][2]), "v"(p[2 * kc][3]));
    asm("v_cvt_pk_bf16_f32 %0, %1, %2" : "=v"(w2) : "v"(p[2 * kc + 1][0]), "v"(p[2 * kc + 1][1]));
    asm("v_cvt_pk_bf16_f32 %0, %1, %2" : "=v"(w3) : "v"(p[2 * kc + 1][2]), "v"(p[2 * kc + 1][3]));
    pw[0] = w0; pw[1] = w1; pw[2] = w2; pw[3] = w3;
    pa[kc] = *(bf16x8*)&pw;
  }
  __builtin_amdgcn_s_setprio(1);
#pragma unroll
  for (int kc = 0; kc < 4; kc++) {
#pragma unroll
    for (int c = 0; c < 4; c++) {
      const __hip_bfloat16* vr = Vs + (c * 16 + r) * 128 + (((kc * 4 + q) ^ r7) * 8);
      bf16x8 vf = *(const bf16x8*)vr;
      o[c] = __builtin_amdgcn_mfma_f32_16x16x32_bf16(pa[kc], vf, o[c], 0, 0, 0);
    }
    ls = __builtin_amdgcn_mfma_f32_16x16x32_bf16(pa[kc], onesf, ls, 0, 0, 0);
  }
  __builtin_amdgcn_s_setprio(0);
}

__global__ __launch_bounds__(512, 4) void attn_kernel(const __hip_bfloat16* __restrict__ qkv,
                                                      const __hip_bfloat16* __restrict__ vt,
                                                      const float* __restrict__ biasH,
                                                      __hip_bfloat16* __restrict__ out) {
  const int blk = blockIdx.x;
  const int bh = blk & 15;
  const int pr = blk >> 4;  // 0..31
  const int b = bh >> 3, h = bh & 7;
  const int tid = threadIdx.x, lane = tid & 63, w = tid >> 6;  // w 0..7
  const int grp = w >> 2, wg = w & 3;
  const int qi = grp ? (63 - pr) : pr;
  const int l0 = qi * 64;
  const int lw0 = l0 + wg * 16;
  const int r = lane & 15, q = lane >> 4;

  __shared__ __align__(16) __hip_bfloat16 Ksm[2][128 * 64];
  __shared__ __align__(16) __hip_bfloat16 Vsm[2][64 * 128];
  __shared__ __align__(16) float biasLds[4096];

  const float LOG2E = 1.4426950408889634f;
  const float scale2 = 0.125f * LOG2E;

  const __hip_bfloat16* Kg = qkv + (size_t)b * L_SEQ * QKV_LD + 512 + h * 64;
  const __hip_bfloat16* Vg = vt + (size_t)bh * 64 * L_SEQ;
  const float* biasHp = biasH + (size_t)bh * L_SEQ;

  stage_kv128(w, lane, 0, Kg, Vg, Ksm[0], Vsm[0]);
#pragma unroll
  for (int ii = 0; ii < 2; ii++) {
    const int fo = (w * 2 + ii) * 256;
    gl_lds16((const __hip_bfloat16*)(biasHp + fo + lane * 4),
             (__hip_bfloat16*)(biasLds + fo + lane * 4));
  }

  bf16x8 qf0, qf1;
  {
    const __hip_bfloat16* qrow = qkv + (size_t)(b * L_SEQ + lw0 + r) * QKV_LD + h * 64 + q * 8;
    qf0 = *(const bf16x8*)qrow;
    qf1 = *(const bf16x8*)(qrow + 32);
  }

  const f32x4 zz = {0.f, 0.f, 0.f, 0.f};
  f32x4 o[4];
  for (int c = 0; c < 4; c++) o[c] = zz;
  f32x4 ls = zz;

  bf16x8 onesf;
  for (int i = 0; i < 8; i++) ((short*)&onesf)[i] = (short)0x3F80;  // bf16 1.0

  const int ntA = (pr >> 1) + 1;
  const int ntB = ((63 - pr) >> 1) + 1;
  const int nt = grp ? ntB : ntA;

  for (int t = 0; t < ntB; t++) {
    const int cur = t & 1;
    if (t + 1 < ntB) {
      stage_kv128(w, lane, (t + 1) << 7, Kg, Vg, Ksm[cur ^ 1], Vsm[cur ^ 1]);
      asm volatile("s_waitcnt vmcnt(4)" ::: "memory");
    } else {
      asm volatile("s_waitcnt vmcnt(0)" ::: "memory");
    }
    __builtin_amdgcn_s_barrier();
    if (t < nt) {
      if (t == nt - 1)
        attn_tile128<true>(t << 7, lw0, r, q, Ksm[cur], Vsm[cur], biasLds, scale2, qf0, qf1,
                           onesf, o, ls);
      else
        attn_tile128<false>(t << 7, lw0, r, q, Ksm[cur], Vsm[cur], biasLds, scale2, qf0, qf1,
                            onesf, o, ls);
    }
    __builtin_amdgcn_s_barrier();
  }

  float invj[4];
  for (int j = 0; j < 4; j++) invj[j] = 1.0f / ls[j];
  for (int c = 0; c < 4; c++)
    for (int j = 0; j < 4; j++) {
      const int rowg = lw0 + q * 4 + j;
      out[(size_t)(b * L_SEQ + rowg) * D_MODEL + h * 64 + c * 16 + r] = f2bf(o[c][j] * invj[j]);
    }
}

// ---------------- Launch ----------------
extern "C" void kernel_launch(void* const* d_in, const int* in_sizes, int n_in,
                              void* d_out, int out_size, void* d_ws, size_t ws_size,
                              hipStream_t stream) {
  const float* x = (const float*)d_in[0];
  const float* ts = (const float*)d_in[1];
  const float* mask = (const float*)d_in[2];
  const float* ln1_g = (const float*)d_in[3];
  const float* ln1_b = (const float*)d_in[4];
  const float* w_qkv = (const float*)d_in[5];
  const float* w_out = (const float*)d_in[6];
  const float* decay = (const float*)d_in[7];
  const float* ln2_g = (const float*)d_in[8];
  const float* ln2_b = (const float*)d_in[9];
  const float* w_ff1 = (const float*)d_in[10];
  const float* w_ff2 = (const float*)d_in[11];

  char* ws = (char*)d_ws;
  // layout (bytes) — total footprint 65,011,712:
  //   [0, 6M)    weights bf16
  //   [6M, 14M)  xn (dead after gemm0)
  //   [14M, 38M) qkv Q/K regions (dead after attn); V region never written (fused to vt)
  //   [38M, 46M) attnout -> h
  //   [46M, 62M) x2 (fp32). Overlaid at its head (disjoint lifetimes, all dead before
  //              gemm<1> writes x2): biasH (256KB) then vt (8MB).
  //   ff1out overlays [6M, 38M)
  __hip_bfloat16* wqkv_b = (__hip_bfloat16*)(ws + 0);
  __hip_bfloat16* wout_b = (__hip_bfloat16*)(ws + 1572864);
  __hip_bfloat16* wff1_b = (__hip_bfloat16*)(ws + 2097152);
  __hip_bfloat16* wff2_b = (__hip_bfloat16*)(ws + 4194304);
  __hip_bfloat16* xn = (__hip_bfloat16*)(ws + 6291456);
  __hip_bfloat16* qkv = (__hip_bfloat16*)(ws + 14680064);
  __hip_bfloat16* attnout = (__hip_bfloat16*)(ws + 39845888);
  __hip_bfloat16* h = attnout;
  __hip_bfloat16* ff1out = (__hip_bfloat16*)(ws + 6291456);
  float* x2 = (float*)(ws + 48234496);
  float* biasH = (float*)(ws + 48234496);                  // [46M, +256KB)
  __hip_bfloat16* vt = (__hip_bfloat16*)(ws + 48496640);   // [46M+256KB, +8MB)
  float* out = (float*)d_out;

  const int M = 2 * L_SEQ;  // 8192

  prep_kernel<<<dim3(11520), dim3(256), 0, stream>>>(w_qkv, wqkv_b, w_out, wout_b,
                                                     w_ff1, wff1_b, w_ff2, wff2_b,
                                                     ts, mask, decay, biasH,
                                                     x, ln1_g, ln1_b, xn);

  gemm_kernel<4><<<dim3(12, 64), dim3(256), 0, stream>>>(xn, wqkv_b, M, 1536, 512, vt, qkv);
  attn_kernel<<<dim3(512), dim3(512), 0, stream>>>(qkv, vt, biasH, attnout);
  gemm_res64_kernel<<<dim3(4, 128), dim3(256), 0, stream>>>(attnout, wout_b, M, 512, 512, x, x2);
  ln_kernel<<<dim3(M), dim3(256), 0, stream>>>(x2, ln2_g, ln2_b, h);
  gemm256_silu_kernel<<<dim3(16, 32), dim3(512), 0, stream>>>(h, wff1_b, M, 2048, 512, ff1out);
  gemm_res64_kernel<<<dim3(4, 128), dim3(256), 0, stream>>>(ff1out, wff2_b, M, 512, 2048, x2, out);
}

// Round 14
// 256.323 us; speedup vs baseline: 1.0686x; 1.0154x over previous
//
#include <hip/hip_runtime.h>
#include <hip/hip_bf16.h>
#include <cmath>

// SparseAttentionBlock: B=2, L=4096, D=512, H=8, dh=64
// Inputs/outputs fp32; internal GEMM pipeline bf16; residual spine fp32.

#define L_SEQ 4096
#define D_MODEL 512
#define N_HEADS 8
#define D_HEAD 64
#define QKV_LD 1536

typedef __attribute__((ext_vector_type(8))) short bf16x8;
typedef __attribute__((ext_vector_type(4))) float f32x4;
typedef __attribute__((ext_vector_type(4))) unsigned u32x4;

__device__ __forceinline__ __hip_bfloat16 f2bf(float v) { return __float2bfloat16(v); }

__device__ __forceinline__ float exp2_raw(float x) {
  float r;
  asm("v_exp_f32 %0, %1" : "=v"(r) : "v"(x));
  return r;  // 2^x, HW transcendental
}

__device__ __forceinline__ void gl_lds16(const __hip_bfloat16* g, __hip_bfloat16* l) {
  __builtin_amdgcn_global_load_lds((__attribute__((address_space(1))) void*)g,
                                   (__attribute__((address_space(3))) void*)l, 16, 0, 0);
}

// ---------------- prep: weight cvt (fp32->bf16) + bias prep + LN1, ONE launch ------------
__global__ __launch_bounds__(256) void prep_kernel(const float* __restrict__ s0, __hip_bfloat16* __restrict__ d0,
                                                   const float* __restrict__ s1, __hip_bfloat16* __restrict__ d1,
                                                   const float* __restrict__ s2, __hip_bfloat16* __restrict__ d2,
                                                   const float* __restrict__ s3, __hip_bfloat16* __restrict__ d3,
                                                   const float* __restrict__ ts,
                                                   const float* __restrict__ mask,
                                                   const float* __restrict__ decay_rate,
                                                   float* __restrict__ biasH,
                                                   const float* __restrict__ x,
                                                   const float* __restrict__ ln1_g,
                                                   const float* __restrict__ ln1_b,
                                                   __hip_bfloat16* __restrict__ xn) {
  if (blockIdx.x < 3328) {
    const int i = blockIdx.x * 256 + threadIdx.x;
    if (i < 786432) {
      const float* s;
      __hip_bfloat16* d;
      int off;
      if (i < 196608) { s = s0; d = d0; off = i; }
      else if (i < 262144) { s = s1; d = d1; off = i - 196608; }
      else if (i < 524288) { s = s2; d = d2; off = i - 262144; }
      else { s = s3; d = d3; off = i - 524288; }
      const float4 v = ((const float4*)s)[off];
      d[4 * off + 0] = f2bf(v.x);
      d[4 * off + 1] = f2bf(v.y);
      d[4 * off + 2] = f2bf(v.z);
      d[4 * off + 3] = f2bf(v.w);
    } else {
      const int idx = i - 786432;  // 65536 = 2*8*4096
      const int col = idx & 4095;
      const int h = (idx >> 12) & 7;
      const int b = idx >> 15;
      const float LOG2E = 1.4426950408889634f;
      const float dfac = log1pf(expf(decay_rate[h])) * (1.0f / 24.0f) * LOG2E;
      const float m = mask[b * 4096 + col];
      biasH[idx] = dfac * ts[b * 4096 + col] + (m != 0.f ? 0.f : -1e30f);
    }
  } else {
    const int row = blockIdx.x - 3328;
    const int t = threadIdx.x;
    const float* xr = x + (size_t)row * D_MODEL;
    float v0 = xr[t];
    float v1 = xr[t + 256];
    float s = v0 + v1;
    float qq = v0 * v0 + v1 * v1;
    for (int off = 32; off > 0; off >>= 1) {
      s += __shfl_xor(s, off);
      qq += __shfl_xor(qq, off);
    }
    __shared__ float red[8];
    const int wid = t >> 6;
    if ((t & 63) == 0) { red[wid] = s; red[4 + wid] = qq; }
    __syncthreads();
    s = red[0] + red[1] + red[2] + red[3];
    qq = red[4] + red[5] + red[6] + red[7];
    const float mu = s * (1.0f / 512.0f);
    const float var = fmaxf(qq * (1.0f / 512.0f) - mu * mu, 0.0f);
    const float rstd = rsqrtf(var + 1e-5f);
    __hip_bfloat16* orow = xn + (size_t)row * D_MODEL;
    orow[t] = f2bf((v0 - mu) * rstd * ln1_g[t] + ln1_b[t]);
    orow[t + 256] = f2bf((v1 - mu) * rstd * ln1_g[t + 256] + ln1_b[t + 256]);
  }
}

// ---------------- LayerNorm: fp32 in -> bf16 out (ln2) ----------------
__global__ __launch_bounds__(256) void ln_kernel(const float* __restrict__ x,
                                                 const float* __restrict__ g,
                                                 const float* __restrict__ b,
                                                 __hip_bfloat16* __restrict__ out) {
  const int row = blockIdx.x;
  const int t = threadIdx.x;
  const float* xr = x + (size_t)row * D_MODEL;
  float v0 = xr[t];
  float v1 = xr[t + 256];
  float s = v0 + v1;
  float qq = v0 * v0 + v1 * v1;
  for (int off = 32; off > 0; off >>= 1) {
    s += __shfl_xor(s, off);
    qq += __shfl_xor(qq, off);
  }
  __shared__ float red[8];
  const int wid = t >> 6;
  if ((t & 63) == 0) { red[wid] = s; red[4 + wid] = qq; }
  __syncthreads();
  s = red[0] + red[1] + red[2] + red[3];
  qq = red[4] + red[5] + red[6] + red[7];
  const float mu = s * (1.0f / 512.0f);
  const float var = fmaxf(qq * (1.0f / 512.0f) - mu * mu, 0.0f);
  const float rstd = rsqrtf(var + 1e-5f);
  __hip_bfloat16* orow = out + (size_t)row * D_MODEL;
  orow[t] = f2bf((v0 - mu) * rstd * g[t] + b[t]);
  orow[t + 256] = f2bf((v1 - mu) * rstd * g[t + 256] + b[t + 256]);
}

// ---------------- GEMM 128x128 (2-barrier double-buffer — proven optimum) ---------------
// EPI 0: store bf16
// EPI 4 (gemm0+vtrans fusion): n0<1024 -> qkv store; n0>=1024 -> V direct to
//   vt[b,h,dh, sigma-permuted L]; sigma: [.][a2][q1][q0][a1][a0]->[.][q1][q0][a2][a1][a0].
template <int EPI>
__global__ __launch_bounds__(256) void gemm_kernel(const __hip_bfloat16* __restrict__ A,
                                                   const __hip_bfloat16* __restrict__ B,
                                                   int M, int N, int K,
                                                   __hip_bfloat16* __restrict__ vtout,
                                                   void* __restrict__ C) {
  __shared__ __align__(16) __hip_bfloat16 As[2][128 * 32];
  __shared__ __align__(16) __hip_bfloat16 Bs[2][128 * 32];
  const int tid = threadIdx.x;
  const int lane = tid & 63, w = tid >> 6;
  const int m0 = blockIdx.y * 128, n0 = blockIdx.x * 128;
  const int wm = (w >> 1) * 64, wn = (w & 1) * 64;
  const int r = lane & 15, q = lane >> 4;

  f32x4 acc[4][4];
  const f32x4 zz = {0.f, 0.f, 0.f, 0.f};
  for (int i = 0; i < 4; i++)
    for (int j = 0; j < 4; j++) acc[i][j] = zz;

  const int c0 = tid, c1 = 256 + tid;
  const int row0 = c0 >> 2, kb0 = (c0 & 3) * 8;
  const int row1 = c1 >> 2, kb1 = (c1 & 3) * 8;

#define GEMM_STAGE(k0, buf)                                                     \
  do {                                                                          \
    gl_lds16(A + (size_t)(m0 + row0) * K + ((k0) + kb0), &As[buf][c0 * 8]);     \
    gl_lds16(B + (size_t)(n0 + row0) * K + ((k0) + kb0), &Bs[buf][c0 * 8]);     \
    gl_lds16(A + (size_t)(m0 + row1) * K + ((k0) + kb1), &As[buf][c1 * 8]);     \
    gl_lds16(B + (size_t)(n0 + row1) * K + ((k0) + kb1), &Bs[buf][c1 * 8]);     \
  } while (0)

  GEMM_STAGE(0, 0);
  const int niter = K >> 5;
  for (int it = 0; it < niter; it++) {
    const int cur = it & 1;
    if (it + 1 < niter) {
      GEMM_STAGE((it + 1) << 5, cur ^ 1);
      asm volatile("s_waitcnt vmcnt(4)" ::: "memory");  // own iter-it loads retired
    } else {
      asm volatile("s_waitcnt vmcnt(0)" ::: "memory");
    }
    __builtin_amdgcn_s_barrier();  // all waves' iter-it stage complete
    bf16x8 af[4], bfr[4];
    for (int mi = 0; mi < 4; mi++)
      af[mi] = *(const bf16x8*)(&As[cur][(wm + mi * 16 + r) * 32 + q * 8]);
    for (int ni = 0; ni < 4; ni++)
      bfr[ni] = *(const bf16x8*)(&Bs[cur][(wn + ni * 16 + r) * 32 + q * 8]);
    for (int mi = 0; mi < 4; mi++)
      for (int ni = 0; ni < 4; ni++)
        acc[mi][ni] = __builtin_amdgcn_mfma_f32_16x16x32_bf16(af[mi], bfr[ni], acc[mi][ni], 0, 0, 0);
    __builtin_amdgcn_s_barrier();  // reads of buf[cur] done before it+1 overwrites it
  }
#undef GEMM_STAGE

  for (int mi = 0; mi < 4; mi++)
    for (int ni = 0; ni < 4; ni++)
      for (int j = 0; j < 4; j++) {
        const int gm = m0 + wm + mi * 16 + q * 4 + j;
        const int gn = n0 + wn + ni * 16 + r;
        float v = acc[mi][ni][j];
        const size_t idx = (size_t)gm * N + gn;
        if (EPI == 0) {
          ((__hip_bfloat16*)C)[idx] = f2bf(v);
        } else {  // EPI == 4
          if (n0 < 1024) {
            ((__hip_bfloat16*)C)[idx] = f2bf(v);
          } else {
            const int bb = gm >> 12, ll = gm & 4095;
            const int hd = gn - 1024;  // h*64 + d
            const int kin = ll & 63;
            const int sl = (kin & 0x23) | ((kin & 0x10) >> 2) | ((kin & 0x0c) << 1);
            vtout[(size_t)(bb * 512 + hd) * 4096 + (ll & ~63) + sl] = f2bf(v);
          }
        }
      }
}

// ---------------- GEMM 256x128 + silu (gemm2): 2x arithmetic intensity per staged byte --
__global__ __launch_bounds__(512, 4) void gemm256_silu_kernel(const __hip_bfloat16* __restrict__ A,
                                                              const __hip_bfloat16* __restrict__ B,
                                                              int M, int N, int K,
                                                              __hip_bfloat16* __restrict__ C) {
  __shared__ __align__(16) __hip_bfloat16 As[2][256 * 32];
  __shared__ __align__(16) __hip_bfloat16 Bs[2][128 * 32];
  const int tid = threadIdx.x;
  const int lane = tid & 63, w = tid >> 6;
  const int m0 = blockIdx.y * 256, n0 = blockIdx.x * 128;
  const int wm = (w >> 1) * 64, wn = (w & 1) * 64;
  const int r = lane & 15, q = lane >> 4;

  f32x4 acc[4][4];
  const f32x4 zz = {0.f, 0.f, 0.f, 0.f};
  for (int i = 0; i < 4; i++)
    for (int j = 0; j < 4; j++) acc[i][j] = zz;

#define GEMM_STAGE256(k0, buf)                                                        \
  do {                                                                                \
    _Pragma("unroll")                                                                 \
    for (int i = 0; i < 3; i++) {                                                     \
      const int l = i * 512 + tid;                                                    \
      if (l < 1024) {                                                                 \
        gl_lds16(A + (size_t)(m0 + (l >> 2)) * K + ((k0) + (l & 3) * 8),              \
                 &As[buf][l * 8]);                                                    \
      } else {                                                                        \
        const int lb = l - 1024;                                                      \
        gl_lds16(B + (size_t)(n0 + (lb >> 2)) * K + ((k0) + (lb & 3) * 8),            \
                 &Bs[buf][lb * 8]);                                                   \
      }                                                                               \
    }                                                                                 \
  } while (0)

  GEMM_STAGE256(0, 0);
  const int niter = K >> 5;
  for (int it = 0; it < niter; it++) {
    const int cur = it & 1;
    if (it + 1 < niter) {
      GEMM_STAGE256((it + 1) << 5, cur ^ 1);
      asm volatile("s_waitcnt vmcnt(3)" ::: "memory");  // own iter-it loads retired
    } else {
      asm volatile("s_waitcnt vmcnt(0)" ::: "memory");
    }
    __builtin_amdgcn_s_barrier();
    bf16x8 af[4], bfr[4];
    for (int mi = 0; mi < 4; mi++)
      af[mi] = *(const bf16x8*)(&As[cur][(wm + mi * 16 + r) * 32 + q * 8]);
    for (int ni = 0; ni < 4; ni++)
      bfr[ni] = *(const bf16x8*)(&Bs[cur][(wn + ni * 16 + r) * 32 + q * 8]);
    for (int mi = 0; mi < 4; mi++)
      for (int ni = 0; ni < 4; ni++)
        acc[mi][ni] = __builtin_amdgcn_mfma_f32_16x16x32_bf16(af[mi], bfr[ni], acc[mi][ni], 0, 0, 0);
    __builtin_amdgcn_s_barrier();
  }
#undef GEMM_STAGE256

  for (int mi = 0; mi < 4; mi++)
    for (int ni = 0; ni < 4; ni++)
      for (int j = 0; j < 4; j++) {
        const int gm = m0 + wm + mi * 16 + q * 4 + j;
        const int gn = n0 + wn + ni * 16 + r;
        float v = acc[mi][ni][j];
        v = v / (1.0f + expf(-v));
        C[(size_t)gm * N + gn] = f2bf(v);
      }
}

// ---------------- GEMM 64x128 (+residual) v2: 8 waves + BK=64 ---------------------------
// Same 2-barrier double-buffer shape; two proven levers: (1) 512-thread blocks -> 512
// blocks = 2/CU x 8 waves = 4 waves/SIMD (R8's TLP lever, was 2); (2) BK=64 halves
// barrier count (gemm3: 64->32 iters). BK=64 rows are 128B -> would be a 16-way bank
// conflict; fixed T21-style: global source chunk pre-swizzled cs = c ^ (row&7), LDS
// linear, same XOR on the read side ((ks*4+q) ^ (r&7)) — identical to attn's K staging.
// LDS 48KB. Wave (2m x 4n) owns 32x32: acc[2][2]. 3 gl_lds/thread -> vmcnt(3).
__global__ __launch_bounds__(512, 4) void gemm_res64_kernel(const __hip_bfloat16* __restrict__ A,
                                                            const __hip_bfloat16* __restrict__ B,
                                                            int M, int N, int K,
                                                            const float* __restrict__ aux,
                                                            float* __restrict__ C) {
  __shared__ __align__(16) __hip_bfloat16 As[2][64 * 64];
  __shared__ __align__(16) __hip_bfloat16 Bs[2][128 * 64];
  const int tid = threadIdx.x;
  const int lane = tid & 63, w = tid >> 6;  // w 0..7
  const int m0 = blockIdx.y * 64, n0 = blockIdx.x * 128;
  const int wm = (w >> 2) * 32, wn = (w & 3) * 32;
  const int r = lane & 15, q = lane >> 4;
  const int r7 = r & 7;

  f32x4 acc[2][2];
  const f32x4 zz = {0.f, 0.f, 0.f, 0.f};
  for (int i = 0; i < 2; i++)
    for (int j = 0; j < 2; j++) acc[i][j] = zz;

  // stage: 1536 16B-chunks (A: 64 rows x 8, B: 128 rows x 8), 3 per thread.
#define GEMM_STAGE64(k0, buf)                                                         \
  do {                                                                               \
    _Pragma("unroll")                                                                \
    for (int i = 0; i < 3; i++) {                                                    \
      const int l = i * 512 + tid;                                                   \
      if (l < 512) {                                                                 \
        const int row = l >> 3, cs = (l & 7) ^ (row & 7);                            \
        gl_lds16(A + (size_t)(m0 + row) * K + ((k0) + cs * 8), &As[buf][l * 8]);     \
      } else {                                                                       \
        const int lb = l - 512;                                                      \
        const int row = lb >> 3, cs = (lb & 7) ^ (row & 7);                          \
        gl_lds16(B + (size_t)(n0 + row) * K + ((k0) + cs * 8), &Bs[buf][lb * 8]);    \
      }                                                                              \
    }                                                                                \
  } while (0)

  GEMM_STAGE64(0, 0);
  const int niter = K >> 6;
  for (int it = 0; it < niter; it++) {
    const int cur = it & 1;
    if (it + 1 < niter) {
      GEMM_STAGE64((it + 1) << 6, cur ^ 1);
      asm volatile("s_waitcnt vmcnt(3)" ::: "memory");  // own iter-it loads retired
    } else {
      asm volatile("s_waitcnt vmcnt(0)" ::: "memory");
    }
    __builtin_amdgcn_s_barrier();
#pragma unroll
    for (int ks = 0; ks < 2; ks++) {
      bf16x8 af[2], bfr[2];
#pragma unroll
      for (int mi = 0; mi < 2; mi++)
        af[mi] = *(const bf16x8*)(&As[cur][(wm + mi * 16 + r) * 64 + (((ks * 4 + q) ^ r7) * 8)]);
#pragma unroll
      for (int ni = 0; ni < 2; ni++)
        bfr[ni] = *(const bf16x8*)(&Bs[cur][(wn + ni * 16 + r) * 64 + (((ks * 4 + q) ^ r7) * 8)]);
#pragma unroll
      for (int mi = 0; mi < 2; mi++)
#pragma unroll
        for (int ni = 0; ni < 2; ni++)
          acc[mi][ni] = __builtin_amdgcn_mfma_f32_16x16x32_bf16(af[mi], bfr[ni], acc[mi][ni], 0, 0, 0);
    }
    __builtin_amdgcn_s_barrier();
  }
#undef GEMM_STAGE64

  for (int mi = 0; mi < 2; mi++)
    for (int ni = 0; ni < 2; ni++)
      for (int j = 0; j < 4; j++) {
        const int gm = m0 + wm + mi * 16 + q * 4 + j;
        const int gn = n0 + wn + ni * 16 + r;
        const size_t idx = (size_t)gm * N + gn;
        C[idx] = acc[mi][ni][j] + aux[idx];
      }
}

// ---------------- Flash attention (R8 config — proven ~58 us, unchanged) ----------------
__device__ __forceinline__ void stage_kv128(int w, int lane, int key0,
                                            const __hip_bfloat16* __restrict__ Kg,
                                            const __hip_bfloat16* __restrict__ Vg,
                                            __hip_bfloat16* Ks, __hip_bfloat16* Vs) {
  const int krow_in = lane >> 3;
  const int kcs = (lane & 7) ^ krow_in;
  const int vrow_in = lane >> 4;
  const int vch = lane & 15;
#pragma unroll
  for (int ii = 0; ii < 2; ii++) {
    const int i = w * 2 + ii;
    const int krow = i * 8 + krow_in;  // 0..127
    gl_lds16(Kg + (size_t)(key0 + krow) * QKV_LD + kcs * 8, Ks + i * 512 + lane * 8);
    const int vrow = i * 4 + vrow_in;  // 0..63
    const int vcs = vch ^ (vrow & 7);
    gl_lds16(Vg + (size_t)vrow * L_SEQ + key0 + vcs * 8, Vs + i * 512 + lane * 8);
  }
}

template <bool CAUSAL>
__device__ __forceinline__ void attn_tile128(int key0, int lw0, int r, int q,
                                             const __hip_bfloat16* Ks,
                                             const __hip_bfloat16* Vs,
                                             const float* biasLds,
                                             float scale2,
                                             const bf16x8& qf0, const bf16x8& qf1,
                                             const bf16x8& onesf,
                                             f32x4* o, f32x4& ls) {
  const int r7 = r & 7;
  const f32x4 zz = {0.f, 0.f, 0.f, 0.f};
  f32x4 bias4[8];
#pragma unroll
  for (int hc = 0; hc < 8; hc++)
    bias4[hc] = *(const f32x4*)(biasLds + key0 + hc * 16 + q * 4);
  f32x4 s[8];
  __builtin_amdgcn_s_setprio(1);
#pragma unroll
  for (int hc = 0; hc < 8; hc++) {
    const __hip_bfloat16* kr = Ks + (hc * 16 + r) * 64;
    bf16x8 k0 = *(const bf16x8*)(kr + ((q ^ r7) * 8));
    bf16x8 k1 = *(const bf16x8*)(kr + (((q + 4) ^ r7) * 8));
    f32x4 a = zz;
    a = __builtin_amdgcn_mfma_f32_16x16x32_bf16(k0, qf0, a, 0, 0, 0);
    a = __builtin_amdgcn_mfma_f32_16x16x32_bf16(k1, qf1, a, 0, 0, 0);
    s[hc] = a;
  }
  __builtin_amdgcn_s_setprio(0);
  float p[8][4];
#pragma unroll
  for (int hc = 0; hc < 8; hc++)
#pragma unroll
    for (int j = 0; j < 4; j++) {
      float pv = exp2_raw(fmaf(s[hc][j], scale2, bias4[hc][j]));
      if (CAUSAL) pv = (key0 + hc * 16 + q * 4 + j <= lw0 + r) ? pv : 0.f;
      p[hc][j] = pv;
    }
  bf16x8 pa[4];
#pragma unroll
  for (int kc = 0; kc < 4; kc++) {
    u32x4 pw;
    unsigned w0, w1, w2, w3;
    asm("v_cvt_pk_bf16_f32 %0, %1, %2" : "=v"(w0) : "v"(p[2 * kc][0]), "v"(p[2 * kc][1]));
    asm("v_cvt_pk_bf16_f32 %0, %1, %2" : "=v"(w1) : "v"(p[2 * kc][2]), "v"(p[2 * kc][3]));
    asm("v_cvt_pk_bf16_f32 %0, %1, %2" : "=v"(w2) : "v"(p[2 * kc + 1][0]), "v"(p[2 * kc + 1][1]));
    asm("v_cvt_pk_bf16_f32 %0, %1, %2" : "=v"(w3) : "v"(p[2 * kc + 1][2]), "v"(p[2 * kc + 1][3]));
    pw[0] = w0; pw[1] = w1; pw[2] = w2; pw[3] = w3;
    pa[kc] = *(bf16x8*)&pw;
  }
  __builtin_amdgcn_s_setprio(1);
#pragma unroll
  for (int kc = 0; kc < 4; kc++) {
#pragma unroll
    for (int c = 0; c < 4; c++) {
      const __hip_bfloat16* vr = Vs + (c * 16 + r) * 128 + (((kc * 4 + q) ^ r7) * 8);
      bf16x8 vf = *(const bf16x8*)vr;
      o[c] = __builtin_amdgcn_mfma_f32_16x16x32_bf16(pa[kc], vf, o[c], 0, 0, 0);
    }
    ls = __builtin_amdgcn_mfma_f32_16x16x32_bf16(pa[kc], onesf, ls, 0, 0, 0);
  }
  __builtin_amdgcn_s_setprio(0);
}

__global__ __launch_bounds__(512, 4) void attn_kernel(const __hip_bfloat16* __restrict__ qkv,
                                                      const __hip_bfloat16* __restrict__ vt,
                                                      const float* __restrict__ biasH,
                                                      __hip_bfloat16* __restrict__ out) {
  const int blk = blockIdx.x;
  const int bh = blk & 15;
  const int pr = blk >> 4;  // 0..31
  const int b = bh >> 3, h = bh & 7;
  const int tid = threadIdx.x, lane = tid & 63, w = tid >> 6;  // w 0..7
  const int grp = w >> 2, wg = w & 3;
  const int qi = grp ? (63 - pr) : pr;
  const int l0 = qi * 64;
  const int lw0 = l0 + wg * 16;
  const int r = lane & 15, q = lane >> 4;

  __shared__ __align__(16) __hip_bfloat16 Ksm[2][128 * 64];
  __shared__ __align__(16) __hip_bfloat16 Vsm[2][64 * 128];
  __shared__ __align__(16) float biasLds[4096];

  const float LOG2E = 1.4426950408889634f;
  const float scale2 = 0.125f * LOG2E;

  const __hip_bfloat16* Kg = qkv + (size_t)b * L_SEQ * QKV_LD + 512 + h * 64;
  const __hip_bfloat16* Vg = vt + (size_t)bh * 64 * L_SEQ;
  const float* biasHp = biasH + (size_t)bh * L_SEQ;

  stage_kv128(w, lane, 0, Kg, Vg, Ksm[0], Vsm[0]);
#pragma unroll
  for (int ii = 0; ii < 2; ii++) {
    const int fo = (w * 2 + ii) * 256;
    gl_lds16((const __hip_bfloat16*)(biasHp + fo + lane * 4),
             (__hip_bfloat16*)(biasLds + fo + lane * 4));
  }

  bf16x8 qf0, qf1;
  {
    const __hip_bfloat16* qrow = qkv + (size_t)(b * L_SEQ + lw0 + r) * QKV_LD + h * 64 + q * 8;
    qf0 = *(const bf16x8*)qrow;
    qf1 = *(const bf16x8*)(qrow + 32);
  }

  const f32x4 zz = {0.f, 0.f, 0.f, 0.f};
  f32x4 o[4];
  for (int c = 0; c < 4; c++) o[c] = zz;
  f32x4 ls = zz;

  bf16x8 onesf;
  for (int i = 0; i < 8; i++) ((short*)&onesf)[i] = (short)0x3F80;  // bf16 1.0

  const int ntA = (pr >> 1) + 1;
  const int ntB = ((63 - pr) >> 1) + 1;
  const int nt = grp ? ntB : ntA;

  for (int t = 0; t < ntB; t++) {
    const int cur = t & 1;
    if (t + 1 < ntB) {
      stage_kv128(w, lane, (t + 1) << 7, Kg, Vg, Ksm[cur ^ 1], Vsm[cur ^ 1]);
      asm volatile("s_waitcnt vmcnt(4)" ::: "memory");
    } else {
      asm volatile("s_waitcnt vmcnt(0)" ::: "memory");
    }
    __builtin_amdgcn_s_barrier();
    if (t < nt) {
      if (t == nt - 1)
        attn_tile128<true>(t << 7, lw0, r, q, Ksm[cur], Vsm[cur], biasLds, scale2, qf0, qf1,
                           onesf, o, ls);
      else
        attn_tile128<false>(t << 7, lw0, r, q, Ksm[cur], Vsm[cur], biasLds, scale2, qf0, qf1,
                            onesf, o, ls);
    }
    __builtin_amdgcn_s_barrier();
  }

  float invj[4];
  for (int j = 0; j < 4; j++) invj[j] = 1.0f / ls[j];
  for (int c = 0; c < 4; c++)
    for (int j = 0; j < 4; j++) {
      const int rowg = lw0 + q * 4 + j;
      out[(size_t)(b * L_SEQ + rowg) * D_MODEL + h * 64 + c * 16 + r] = f2bf(o[c][j] * invj[j]);
    }
}

// ---------------- Launch ----------------
extern "C" void kernel_launch(void* const* d_in, const int* in_sizes, int n_in,
                              void* d_out, int out_size, void* d_ws, size_t ws_size,
                              hipStream_t stream) {
  const float* x = (const float*)d_in[0];
  const float* ts = (const float*)d_in[1];
  const float* mask = (const float*)d_in[2];
  const float* ln1_g = (const float*)d_in[3];
  const float* ln1_b = (const float*)d_in[4];
  const float* w_qkv = (const float*)d_in[5];
  const float* w_out = (const float*)d_in[6];
  const float* decay = (const float*)d_in[7];
  const float* ln2_g = (const float*)d_in[8];
  const float* ln2_b = (const float*)d_in[9];
  const float* w_ff1 = (const float*)d_in[10];
  const float* w_ff2 = (const float*)d_in[11];

  char* ws = (char*)d_ws;
  // layout (bytes) — total footprint 65,011,712:
  //   [0, 6M)    weights bf16
  //   [6M, 14M)  xn (dead after gemm0)
  //   [14M, 38M) qkv Q/K regions (dead after attn); V region never written (fused to vt)
  //   [38M, 46M) attnout -> h
  //   [46M, 62M) x2 (fp32). Overlaid at its head (disjoint lifetimes, all dead before
  //              gemm<1> writes x2): biasH (256KB) then vt (8MB).
  //   ff1out overlays [6M, 38M)
  __hip_bfloat16* wqkv_b = (__hip_bfloat16*)(ws + 0);
  __hip_bfloat16* wout_b = (__hip_bfloat16*)(ws + 1572864);
  __hip_bfloat16* wff1_b = (__hip_bfloat16*)(ws + 2097152);
  __hip_bfloat16* wff2_b = (__hip_bfloat16*)(ws + 4194304);
  __hip_bfloat16* xn = (__hip_bfloat16*)(ws + 6291456);
  __hip_bfloat16* qkv = (__hip_bfloat16*)(ws + 14680064);
  __hip_bfloat16* attnout = (__hip_bfloat16*)(ws + 39845888);
  __hip_bfloat16* h = attnout;
  __hip_bfloat16* ff1out = (__hip_bfloat16*)(ws + 6291456);
  float* x2 = (float*)(ws + 48234496);
  float* biasH = (float*)(ws + 48234496);                  // [46M, +256KB)
  __hip_bfloat16* vt = (__hip_bfloat16*)(ws + 48496640);   // [46M+256KB, +8MB)
  float* out = (float*)d_out;

  const int M = 2 * L_SEQ;  // 8192

  prep_kernel<<<dim3(11520), dim3(256), 0, stream>>>(w_qkv, wqkv_b, w_out, wout_b,
                                                     w_ff1, wff1_b, w_ff2, wff2_b,
                                                     ts, mask, decay, biasH,
                                                     x, ln1_g, ln1_b, xn);

  gemm_kernel<4><<<dim3(12, 64), dim3(256), 0, stream>>>(xn, wqkv_b, M, 1536, 512, vt, qkv);
  attn_kernel<<<dim3(512), dim3(512), 0, stream>>>(qkv, vt, biasH, attnout);
  gemm_res64_kernel<<<dim3(4, 128), dim3(512), 0, stream>>>(attnout, wout_b, M, 512, 512, x, x2);
  ln_kernel<<<dim3(M), dim3(256), 0, stream>>>(x2, ln2_g, ln2_b, h);
  gemm256_silu_kernel<<<dim3(16, 32), dim3(512), 0, stream>>>(h, wff1_b, M, 2048, 512, ff1out);
  gemm_res64_kernel<<<dim3(4, 128), dim3(512), 0, stream>>>(ff1out, wff2_b, M, 512, 2048, x2, out);
}